// Round 4
// baseline (116.834 us; speedup 1.0000x reference)
//
#include <hip/hip_runtime.h>
#include <math.h>

#define BATCH 4
#define NPTS 8192
#define TB 256              // threads per block
#define TN 8                // n-points per thread (register-blocked)
#define NT (TB * TN)        // 2048 n per block
#define NTILES (NPTS / NT)  // 4
#define MCH 64              // m-chunks -> grid 4*64 x 4 x 2 = 2048 blocks
#define MC (NPTS / MCH)     // 128 m per chunk
#define NBLK (NTILES * MCH * BATCH * 2)  // 2048

// ws: unsigned minbits[2][BATCH][NPTS] (256 KB), then unsigned counter[1]

#define COMPUTE4(q0, q1, q2, q3)                                              \
    _Pragma("unroll") for (int k = 0; k < TN; ++k) {                          \
        float ea = fmaf(a0[k], q0.x, q0.w);                                   \
        ea = fmaf(a1[k], q0.y, ea);                                           \
        ea = fmaf(a2[k], q0.z, ea);                                           \
        float eb = fmaf(a0[k], q1.x, q1.w);                                   \
        eb = fmaf(a1[k], q1.y, eb);                                           \
        eb = fmaf(a2[k], q1.z, eb);                                           \
        rmin[k] = fminf(fminf(ea, eb), rmin[k]);                              \
        float ec = fmaf(a0[k], q2.x, q2.w);                                   \
        ec = fmaf(a1[k], q2.y, ec);                                           \
        ec = fmaf(a2[k], q2.z, ec);                                           \
        float ed = fmaf(a0[k], q3.x, q3.w);                                   \
        ed = fmaf(a1[k], q3.y, ed);                                           \
        ed = fmaf(a2[k], q3.z, ed);                                           \
        rmin[k] = fminf(fminf(ec, ed), rmin[k]);                              \
    }

__global__ __launch_bounds__(TB, 4) void hd_fused(const float* __restrict__ pred,
                                                  const float* __restrict__ gt,
                                                  unsigned* __restrict__ minbits,
                                                  unsigned* __restrict__ counter,
                                                  float* __restrict__ out) {
    const int tid = threadIdx.x;
    const int ntile = blockIdx.x / MCH;
    const int mc = blockIdx.x % MCH;
    const int b = blockIdx.y;
    const int dir = blockIdx.z;

    const float* X = (dir == 0) ? pred + (size_t)b * NPTS * 3 : gt + (size_t)b * NPTS * 3;
    const float* Y = (dir == 0) ? gt + (size_t)b * NPTS * 3 : pred + (size_t)b * NPTS * 3;

    __shared__ float4 tile[MC];  // (y0, y1, y2, |y|^2) — 2 KB
    if (tid < MC) {
        int m = mc * MC + tid;
        float y0 = Y[3 * m], y1 = Y[3 * m + 1], y2 = Y[3 * m + 2];
        tile[tid] = make_float4(y0, y1, y2, y0 * y0 + y1 * y1 + y2 * y2);
    }

    float a0[TN], a1[TN], a2[TN], a3[TN], rmin[TN];
    const int nbase = ntile * NT;
#pragma unroll
    for (int k = 0; k < TN; ++k) {
        int n = nbase + k * TB + tid;
        float x0 = X[3 * n], x1 = X[3 * n + 1], x2 = X[3 * n + 2];
        a0[k] = -2.f * x0;
        a1[k] = -2.f * x1;
        a2[k] = -2.f * x2;
        a3[k] = x0 * x0 + x1 * x1 + x2 * x2;  // added after the inner loop
        rmin[k] = 3.4e38f;
    }
    __syncthreads();

    // m-loop with explicit register-rotated prefetch of the next 4 y-points
    float4 c0 = tile[0], c1 = tile[1], c2 = tile[2], c3 = tile[3];
    for (int m = 0; m < MC - 4; m += 4) {
        float4 n0 = tile[m + 4], n1 = tile[m + 5], n2 = tile[m + 6], n3 = tile[m + 7];
        COMPUTE4(c0, c1, c2, c3)
        c0 = n0; c1 = n1; c2 = n2; c3 = n3;
    }
    COMPUTE4(c0, c1, c2, c3)  // tail (m = MC-4)

    unsigned* mb = minbits + ((size_t)(dir * BATCH + b)) * NPTS + nbase;
#pragma unroll
    for (int k = 0; k < TN; ++k) {
        float v = fmaxf(a3[k] + rmin[k], 0.f);  // add back |x|^2, clamp cancellation
        atomicMin(&mb[k * TB + tid], __float_as_uint(v));
    }

    // ---- last-block-done arrival, then in-kernel final reduce ----
    __syncthreads();  // all this block's atomicMins issued & drained before arrival
    __shared__ int is_last;
    if (tid == 0) {
        __threadfence();  // release: make this block's atomicMins visible device-wide
        unsigned old = atomicAdd(counter, 1u);  // device-scope by default on CDNA
        is_last = (old == (unsigned)(NBLK - 1));
    }
    __syncthreads();
    if (!is_last) return;
    __threadfence();  // acquire: observe all other blocks' atomicMins

    // wave w reduces batch w (both directions), writes out[w] = sqrt(max)
    const int wave = tid >> 6, lane = tid & 63;
    const unsigned long long* p0 =
        (const unsigned long long*)(minbits + (size_t)wave * NPTS);
    const unsigned long long* p1 =
        (const unsigned long long*)(minbits + (size_t)(BATCH + wave) * NPTS);
    unsigned vmax = 0u;
#pragma unroll 4
    for (int j = 0; j < NPTS / 2 / 64; ++j) {  // 64 iters, coalesced 8B agent loads
        unsigned long long u = __hip_atomic_load(&p0[lane + 64 * j], __ATOMIC_RELAXED,
                                                 __HIP_MEMORY_SCOPE_AGENT);
        unsigned long long v = __hip_atomic_load(&p1[lane + 64 * j], __ATOMIC_RELAXED,
                                                 __HIP_MEMORY_SCOPE_AGENT);
        unsigned a = max((unsigned)u, (unsigned)(u >> 32));
        unsigned c = max((unsigned)v, (unsigned)(v >> 32));
        vmax = max(vmax, max(a, c));
    }
#pragma unroll
    for (int off = 32; off > 0; off >>= 1) {
        unsigned o = (unsigned)__shfl_down((int)vmax, off, 64);
        vmax = max(vmax, o);
    }
    if (lane == 0) out[wave] = sqrtf(__uint_as_float(vmax));
}

extern "C" void kernel_launch(void* const* d_in, const int* in_sizes, int n_in,
                              void* d_out, int out_size, void* d_ws, size_t ws_size,
                              hipStream_t stream) {
    const float* pred = (const float*)d_in[0];  // [B, N, 3]
    const float* gt = (const float*)d_in[1];    // [B, M, 3]
    unsigned* minbits = (unsigned*)d_ws;
    unsigned* counter = minbits + 2 * BATCH * NPTS;

    // 0xFFFFFFFF > bits of any finite float -> valid atomicMin(uint) identity
    (void)hipMemsetAsync(minbits, 0xFF, (size_t)2 * BATCH * NPTS * sizeof(unsigned), stream);
    (void)hipMemsetAsync(counter, 0, sizeof(unsigned), stream);
    hd_fused<<<dim3(NTILES * MCH, BATCH, 2), TB, 0, stream>>>(pred, gt, minbits, counter,
                                                              (float*)d_out);
}